// Round 2
// baseline (15995.886 us; speedup 1.0000x reference)
//
#include <hip/hip_runtime.h>
#include <cstdint>
#include <cstddef>

#define NDOM   32768
#define DIN    128
#define DMODEL 256
#define NHEAD  4
#define NLAYER 4
#define DFFN   1024
#define BATCH  64
#define SEQ    672
#define DHEAD  64
#define MROWS  (BATCH*SEQ)   // 43008

// ---------------- small setup kernels ----------------

__global__ void k_zero_counts(int* __restrict__ counts) {
    if (threadIdx.x < BATCH) counts[threadIdx.x] = 0;
}

__global__ void k_pos(const int* __restrict__ idx, int* __restrict__ counts,
                      int* __restrict__ pos) {
    int i = blockIdx.x * blockDim.x + threadIdx.x;
    if (i < NDOM) pos[i] = atomicAdd(&counts[idx[i]], 1);
}

// h[b,0,:] = cls, everything else 0
__global__ void k_init_h(float* __restrict__ h, const float* __restrict__ cls) {
    const float4* cls4 = (const float4*)cls;
    float4* h4 = (float4*)h;
    const int total4 = MROWS * DMODEL / 4;
    for (int f = blockIdx.x * blockDim.x + threadIdx.x; f < total4;
         f += gridDim.x * blockDim.x) {
        int d4 = f & 63;            // 256/4 float4 per row
        int t  = (f >> 6) % SEQ;
        h4[f] = (t == 0) ? cls4[d4] : make_float4(0.f, 0.f, 0.f, 0.f);
    }
}

// x[i,:] = emb[i,:] @ proj_w + proj_b  scattered to h[idx[i], pos[i]+1, :]
__global__ __launch_bounds__(256) void k_proj_scatter(
    const float* __restrict__ emb, const int* __restrict__ idx,
    const int* __restrict__ pos, const float* __restrict__ W,
    const float* __restrict__ bias, float* __restrict__ h)
{
    __shared__ float e[DIN];
    const int i = blockIdx.x;
    const int tid = threadIdx.x;
    if (tid < DIN) e[tid] = emb[(size_t)i * DIN + tid];
    __syncthreads();
    const int p = pos[i] + 1;
    if (p >= SEQ) return;   // reference drops OOB scatter writes
    float acc = bias[tid];
    #pragma unroll 8
    for (int k = 0; k < DIN; ++k) acc = fmaf(e[k], W[k * DMODEL + tid], acc);
    size_t row = (size_t)idx[i] * SEQ + p;
    h[row * DMODEL + tid] = acc;
}

// ---------------- layernorm: one wave per row ----------------

__global__ __launch_bounds__(256) void k_ln(
    const float* __restrict__ x, const float* __restrict__ g,
    const float* __restrict__ bt, float* __restrict__ y)
{
    const int row  = blockIdx.x * 4 + (threadIdx.x >> 6);
    const int lane = threadIdx.x & 63;
    const float4* xr = (const float4*)(x + (size_t)row * DMODEL);
    float4 v = xr[lane];
    float s = v.x + v.y + v.z + v.w;
    #pragma unroll
    for (int off = 32; off >= 1; off >>= 1) s += __shfl_xor(s, off);
    const float m = s * (1.f / DMODEL);
    const float d0 = v.x - m, d1 = v.y - m, d2 = v.z - m, d3 = v.w - m;
    float q = d0*d0 + d1*d1 + d2*d2 + d3*d3;
    #pragma unroll
    for (int off = 32; off >= 1; off >>= 1) q += __shfl_xor(q, off);
    const float rstd = rsqrtf(q * (1.f / DMODEL) + 1e-5f);
    const float4 gv = ((const float4*)g)[lane];
    const float4 bv = ((const float4*)bt)[lane];
    float4 o;
    o.x = d0 * rstd * gv.x + bv.x;
    o.y = d1 * rstd * gv.y + bv.y;
    o.z = d2 * rstd * gv.z + bv.z;
    o.w = d3 * rstd * gv.w + bv.w;
    ((float4*)(y + (size_t)row * DMODEL))[lane] = o;
}

// ---------------- fp32 tiled GEMM: C[M,Nc] = A[M,K] @ W[K,Nc] + bias ----------------
// 64x64 tile, BK=16, 256 threads, 4x4 microtile per thread.

template<bool RELU, bool RESID>
__global__ __launch_bounds__(256) void k_gemm(
    const float* __restrict__ A, const float* __restrict__ W,
    const float* __restrict__ bias, float* __restrict__ C,
    int M, int K, int Nc)
{
    __shared__ float As[16][64];   // [k][m]
    __shared__ float Bs[16][64];   // [k][n]
    const int tid = threadIdx.x;
    const int tx = tid & 15, ty = tid >> 4;
    const int m0 = blockIdx.y * 64, n0 = blockIdx.x * 64;
    const int ar = tid >> 2, ak = (tid & 3) * 4;   // A loader: row, k4
    const int bk = tid >> 4, bn = (tid & 15) * 4;  // B loader: k, n4
    float c[4][4] = {};

    for (int k0 = 0; k0 < K; k0 += 16) {
        float4 av = *(const float4*)&A[(size_t)(m0 + ar) * K + k0 + ak];
        float4 bv = *(const float4*)&W[(size_t)(k0 + bk) * Nc + n0 + bn];
        __syncthreads();
        As[ak + 0][ar] = av.x;
        As[ak + 1][ar] = av.y;
        As[ak + 2][ar] = av.z;
        As[ak + 3][ar] = av.w;
        *(float4*)&Bs[bk][bn] = bv;
        __syncthreads();
        #pragma unroll
        for (int kk = 0; kk < 16; ++kk) {
            float4 a = *(const float4*)&As[kk][ty * 4];
            float4 b = *(const float4*)&Bs[kk][tx * 4];
            c[0][0] = fmaf(a.x, b.x, c[0][0]); c[0][1] = fmaf(a.x, b.y, c[0][1]);
            c[0][2] = fmaf(a.x, b.z, c[0][2]); c[0][3] = fmaf(a.x, b.w, c[0][3]);
            c[1][0] = fmaf(a.y, b.x, c[1][0]); c[1][1] = fmaf(a.y, b.y, c[1][1]);
            c[1][2] = fmaf(a.y, b.z, c[1][2]); c[1][3] = fmaf(a.y, b.w, c[1][3]);
            c[2][0] = fmaf(a.z, b.x, c[2][0]); c[2][1] = fmaf(a.z, b.y, c[2][1]);
            c[2][2] = fmaf(a.z, b.z, c[2][2]); c[2][3] = fmaf(a.z, b.w, c[2][3]);
            c[3][0] = fmaf(a.w, b.x, c[3][0]); c[3][1] = fmaf(a.w, b.y, c[3][1]);
            c[3][2] = fmaf(a.w, b.z, c[3][2]); c[3][3] = fmaf(a.w, b.w, c[3][3]);
        }
    }

    const float4 bi = *(const float4*)&bias[n0 + tx * 4];
    #pragma unroll
    for (int i = 0; i < 4; ++i) {
        float4 o = make_float4(c[i][0] + bi.x, c[i][1] + bi.y,
                               c[i][2] + bi.z, c[i][3] + bi.w);
        if (RELU) {
            o.x = fmaxf(o.x, 0.f); o.y = fmaxf(o.y, 0.f);
            o.z = fmaxf(o.z, 0.f); o.w = fmaxf(o.w, 0.f);
        }
        float* cp = &C[(size_t)(m0 + ty * 4 + i) * Nc + n0 + tx * 4];
        if (RESID) {
            float4 pr = *(const float4*)cp;
            o.x += pr.x; o.y += pr.y; o.z += pr.z; o.w += pr.w;
        }
        *(float4*)cp = o;
    }
}

// ---------------- attention: one wave per query row ----------------
// qkv layout per token (stride 768): [q(256) | k(256) | v(256)], head h at +h*64.
// Keys valid iff 1 <= t <= count[b] (CLS and padding masked).

__global__ __launch_bounds__(256) void k_attn(
    const float* __restrict__ qkv, const int* __restrict__ counts,
    float* __restrict__ out)
{
    __shared__ float qs[4][DHEAD];
    __shared__ float ps[4][SEQ];
    const int wave = threadIdx.x >> 6, lane = threadIdx.x & 63;
    const int b = blockIdx.z, hh = blockIdx.y;
    const int q = blockIdx.x * 4 + wave;
    const int kmax = min(counts[b], SEQ - 1);
    const float* base = qkv + (size_t)b * SEQ * 768;

    qs[wave][lane] = base[(size_t)q * 768 + hh * DHEAD + lane];
    __syncthreads();
    const float4* qp4 = (const float4*)qs[wave];

    float s[11];
    float m = -INFINITY;
    #pragma unroll
    for (int t = 0; t < 11; ++t) {
        const int j = t * 64 + lane;
        float val = -INFINITY;
        if (j >= 1 && j <= kmax) {
            const float4* kp4 = (const float4*)(base + (size_t)j * 768 + 256 + hh * DHEAD);
            float acc = 0.f;
            #pragma unroll
            for (int d4 = 0; d4 < 16; ++d4) {
                float4 kv = kp4[d4], qv = qp4[d4];
                acc += kv.x * qv.x + kv.y * qv.y + kv.z * qv.z + kv.w * qv.w;
            }
            val = acc * 0.125f;   // 1/sqrt(64)
        }
        s[t] = val;
        m = fmaxf(m, val);
    }
    #pragma unroll
    for (int off = 32; off >= 1; off >>= 1) m = fmaxf(m, __shfl_xor(m, off));

    float sum = 0.f;
    #pragma unroll
    for (int t = 0; t < 11; ++t) {
        const int j = t * 64 + lane;
        if (j < SEQ) {
            float p = __expf(s[t] - m);   // exp(-inf - m) = 0 for masked
            ps[wave][j] = p;
            sum += p;
        }
    }
    #pragma unroll
    for (int off = 32; off >= 1; off >>= 1) sum += __shfl_xor(sum, off);
    __syncthreads();
    const float inv = 1.f / sum;

    // PV: lanes split 4-way over keys x 16-way over dim-groups (float4)
    const int kq = lane >> 4, dg = lane & 15;
    float4 acc = make_float4(0.f, 0.f, 0.f, 0.f);
    for (int j = 1 + kq; j <= kmax; j += 4) {
        const float p = ps[wave][j];
        const float4 vv = ((const float4*)(base + (size_t)j * 768 + 512 + hh * DHEAD))[dg];
        acc.x = fmaf(p, vv.x, acc.x);
        acc.y = fmaf(p, vv.y, acc.y);
        acc.z = fmaf(p, vv.z, acc.z);
        acc.w = fmaf(p, vv.w, acc.w);
    }
    #pragma unroll
    for (int off = 16; off <= 32; off <<= 1) {
        acc.x += __shfl_xor(acc.x, off);
        acc.y += __shfl_xor(acc.y, off);
        acc.z += __shfl_xor(acc.z, off);
        acc.w += __shfl_xor(acc.w, off);
    }
    if (kq == 0) {
        float4 o = make_float4(acc.x * inv, acc.y * inv, acc.z * inv, acc.w * inv);
        ((float4*)(out + ((size_t)b * SEQ + q) * DMODEL + hh * DHEAD))[dg] = o;
    }
}

// ---------------- head: relu(cls@w1+b1)@w2+b2, L2-normalized ----------------

__global__ __launch_bounds__(256) void k_head(
    const float* __restrict__ h, const float* __restrict__ w1,
    const float* __restrict__ b1, const float* __restrict__ w2,
    const float* __restrict__ b2, float* __restrict__ out)
{
    __shared__ float cbuf[DMODEL];
    __shared__ float p1[DMODEL];
    __shared__ float p2[3];
    const int b = blockIdx.x, tid = threadIdx.x;
    cbuf[tid] = h[(size_t)b * SEQ * DMODEL + tid];
    __syncthreads();
    float acc = b1[tid];
    #pragma unroll 8
    for (int k = 0; k < DMODEL; ++k) acc = fmaf(cbuf[k], w1[k * DMODEL + tid], acc);
    p1[tid] = fmaxf(acc, 0.f);
    __syncthreads();
    if (tid < 3) {
        float a = b2[tid];
        for (int k = 0; k < DMODEL; ++k) a = fmaf(p1[k], w2[k * 3 + tid], a);
        p2[tid] = a;
    }
    __syncthreads();
    if (tid < 3) {
        float n2 = p2[0]*p2[0] + p2[1]*p2[1] + p2[2]*p2[2];
        out[b * 3 + tid] = p2[tid] * rsqrtf(n2);
    }
}

// ---------------- launch ----------------

extern "C" void kernel_launch(void* const* d_in, const int* in_sizes, int n_in,
                              void* d_out, int out_size, void* d_ws, size_t ws_size,
                              hipStream_t stream) {
    const float* emb   = (const float*)d_in[0];
    const int*   idx   = (const int*)d_in[1];
    const float* projw = (const float*)d_in[4];
    const float* projb = (const float*)d_in[5];
    const float* cls   = (const float*)d_in[6];
    const float* ln1g  = (const float*)d_in[7];
    const float* ln1b  = (const float*)d_in[8];
    const float* qkvw  = (const float*)d_in[9];
    const float* qkvb  = (const float*)d_in[10];
    const float* outw  = (const float*)d_in[11];
    const float* outb  = (const float*)d_in[12];
    const float* ln2g  = (const float*)d_in[13];
    const float* ln2b  = (const float*)d_in[14];
    const float* ff1w  = (const float*)d_in[15];
    const float* ff1b  = (const float*)d_in[16];
    const float* ff2w  = (const float*)d_in[17];
    const float* ff2b  = (const float*)d_in[18];
    const float* h1w   = (const float*)d_in[19];
    const float* h1b   = (const float*)d_in[20];
    const float* h2w   = (const float*)d_in[21];
    const float* h2b   = (const float*)d_in[22];
    float* out = (float*)d_out;

    char* ws = (char*)d_ws;
    int* counts = (int*)ws;                                   // 64 ints (pad to 256B)
    int* pos    = (int*)(ws + 256);                           // NDOM ints
    float* h    = (float*)(ws + 256 + (size_t)NDOM * 4);      // MROWS*256
    float* y    = h + (size_t)MROWS * DMODEL;                 // MROWS*256
    float* big  = y + (size_t)MROWS * DMODEL;                 // MROWS*1024 (qkv / ffn)

    k_zero_counts<<<1, 64, 0, stream>>>(counts);
    k_pos<<<NDOM / 256, 256, 0, stream>>>(idx, counts, pos);
    k_init_h<<<2688, 256, 0, stream>>>(h, cls);
    k_proj_scatter<<<NDOM, 256, 0, stream>>>(emb, idx, pos, projw, projb, h);

    for (int l = 0; l < NLAYER; ++l) {
        k_ln<<<MROWS / 4, 256, 0, stream>>>(h, ln1g + l * DMODEL, ln1b + l * DMODEL, y);
        k_gemm<false, false><<<dim3(12, 672), 256, 0, stream>>>(
            y, qkvw + (size_t)l * DMODEL * 768, qkvb + l * 768, big, MROWS, DMODEL, 768);
        k_attn<<<dim3(SEQ / 4, NHEAD, BATCH), 256, 0, stream>>>(big, counts, y);
        k_gemm<false, true><<<dim3(4, 672), 256, 0, stream>>>(
            y, outw + (size_t)l * DMODEL * DMODEL, outb + l * DMODEL, h, MROWS, DMODEL, DMODEL);
        k_ln<<<MROWS / 4, 256, 0, stream>>>(h, ln2g + l * DMODEL, ln2b + l * DMODEL, y);
        k_gemm<true, false><<<dim3(16, 672), 256, 0, stream>>>(
            y, ff1w + (size_t)l * DMODEL * DFFN, ff1b + l * DFFN, big, MROWS, DMODEL, DFFN);
        k_gemm<false, true><<<dim3(4, 672), 256, 0, stream>>>(
            big, ff2w + (size_t)l * DFFN * DMODEL, ff2b + l * DMODEL, h, MROWS, DFFN, DMODEL);
    }

    k_head<<<BATCH, 256, 0, stream>>>(h, h1w, h1b, h2w, h2b, out);
}

// Round 4
// 1385.929 us; speedup vs baseline: 11.5416x; 11.5416x over previous
//
#include <hip/hip_runtime.h>
#include <cstdint>
#include <cstddef>

#define NDOM   32768
#define DIN    128
#define DMODEL 256
#define NHEAD  4
#define NLAYER 4
#define DFFN   1024
#define BATCH  64
#define SEQ    672
#define DHEAD  64
#define MROWS  (BATCH*SEQ)   // 43008

typedef unsigned short u16;
typedef __attribute__((ext_vector_type(8))) short bf8;   // 8 bf16 (4 VGPRs)
typedef __attribute__((ext_vector_type(4))) float f4;    // MFMA accumulator

__device__ inline u16 f2b(float x) {            // f32 -> bf16 RNE
    union { float f; unsigned u; } c; c.f = x;
    unsigned r = c.u + 0x7fffu + ((c.u >> 16) & 1u);
    return (u16)(r >> 16);
}

__device__ inline void gload16(const void* g, const void* l) {
    __builtin_amdgcn_global_load_lds(
        (const __attribute__((address_space(1))) void*)g,
        (__attribute__((address_space(3))) void*)l, 16, 0, 0);
}

// ---------------- setup ----------------

__global__ void k_zero_counts(int* __restrict__ counts) {
    if (threadIdx.x < BATCH) counts[threadIdx.x] = 0;
}

__global__ void k_pos(const int* __restrict__ idx, int* __restrict__ counts,
                      int* __restrict__ pos) {
    int i = blockIdx.x * blockDim.x + threadIdx.x;
    if (i < NDOM) pos[i] = atomicAdd(&counts[idx[i]], 1);
}

__global__ void k_init_h(float* __restrict__ h, const float* __restrict__ cls) {
    const float4* cls4 = (const float4*)cls;
    float4* h4 = (float4*)h;
    const int total4 = MROWS * DMODEL / 4;
    for (int f = blockIdx.x * blockDim.x + threadIdx.x; f < total4;
         f += gridDim.x * blockDim.x) {
        int d4 = f & 63;
        int t  = (f >> 6) % SEQ;
        h4[f] = (t == 0) ? cls4[d4] : make_float4(0.f, 0.f, 0.f, 0.f);
    }
}

__global__ __launch_bounds__(256) void k_proj_scatter(
    const float* __restrict__ emb, const int* __restrict__ idx,
    const int* __restrict__ pos, const float* __restrict__ W,
    const float* __restrict__ bias, float* __restrict__ h)
{
    __shared__ float e[DIN];
    const int i = blockIdx.x;
    const int tid = threadIdx.x;
    if (tid < DIN) e[tid] = emb[(size_t)i * DIN + tid];
    __syncthreads();
    const int p = pos[i] + 1;
    if (p >= SEQ) return;
    float acc = bias[tid];
    #pragma unroll 8
    for (int k = 0; k < DIN; ++k) acc = fmaf(e[k], W[k * DMODEL + tid], acc);
    size_t row = (size_t)idx[i] * SEQ + p;
    h[row * DMODEL + tid] = acc;
}

// weight convert+transpose: Wt[n][k] = bf16(W[k][n])
__global__ void k_wt(const float* __restrict__ W, u16* __restrict__ Wt,
                     int K, int N) {
    int i = blockIdx.x * 256 + threadIdx.x;
    if (i < N * K) {
        int n = i / K, k = i - n * K;
        Wt[i] = f2b(W[(size_t)k * N + n]);
    }
}

// ---------------- layernorm -> bf16 ----------------

__global__ __launch_bounds__(256) void k_ln_bf(
    const float* __restrict__ x, const float* __restrict__ g,
    const float* __restrict__ bt, u16* __restrict__ y)
{
    const int row  = blockIdx.x * 4 + (threadIdx.x >> 6);
    const int lane = threadIdx.x & 63;
    float4 v = ((const float4*)(x + (size_t)row * DMODEL))[lane];
    float s = v.x + v.y + v.z + v.w;
    #pragma unroll
    for (int off = 32; off >= 1; off >>= 1) s += __shfl_xor(s, off);
    const float m = s * (1.f / DMODEL);
    const float d0 = v.x - m, d1 = v.y - m, d2 = v.z - m, d3 = v.w - m;
    float q = d0*d0 + d1*d1 + d2*d2 + d3*d3;
    #pragma unroll
    for (int off = 32; off >= 1; off >>= 1) q += __shfl_xor(q, off);
    const float rstd = rsqrtf(q * (1.f / DMODEL) + 1e-5f);
    const float4 gv = ((const float4*)g)[lane];
    const float4 bv = ((const float4*)bt)[lane];
    ushort4 o;
    o.x = f2b(d0 * rstd * gv.x + bv.x);
    o.y = f2b(d1 * rstd * gv.y + bv.y);
    o.z = f2b(d2 * rstd * gv.z + bv.z);
    o.w = f2b(d3 * rstd * gv.w + bv.w);
    ((ushort4*)(y + (size_t)row * DMODEL))[lane] = o;
}

// ---------------- bf16 MFMA GEMM: C[M,N] = A[M,K] @ Bt[N,K]^T + bias ----------------
// 128x128 tile, BK=64, 4 waves (2x2), 4x4 16x16x32 fragments per wave.
// LDS rows 128B, XOR-swizzled: slot ^= (row&7).

template<int RELU, int RESID, int OBF>
__global__ __launch_bounds__(256) void k_gemm_bf(
    const u16* __restrict__ A, const u16* __restrict__ Bt,
    const float* __restrict__ bias, float* __restrict__ Cf,
    u16* __restrict__ Cb, int K, int N)
{
    __shared__ u16 As[8192];   // [128][64] bf16, swizzled
    __shared__ u16 Bs[8192];
    const int tid = threadIdx.x;
    const int w = tid >> 6, lane = tid & 63;
    const int lr = lane & 15, lg = lane >> 4;
    const int m0 = blockIdx.y * 128, n0 = blockIdx.x * 128;
    const int wm = (w >> 1) * 64, wn = (w & 1) * 64;

    const f4 zf = {0.f, 0.f, 0.f, 0.f};
    f4 acc[4][4];
    #pragma unroll
    for (int i = 0; i < 4; ++i)
        #pragma unroll
        for (int j = 0; j < 4; ++j) acc[i][j] = zf;

    const int srow8 = lane >> 3;   // 0..7 within chunk
    const int sq = lane & 7;       // 16B slot within row

    for (int k0 = 0; k0 < K; k0 += 64) {
        #pragma unroll
        for (int c = 0; c < 4; ++c) {
            const int chunk = w * 4 + c;               // 0..15 (1KB each)
            const int row = chunk * 8 + srow8;         // 0..127
            const int ks = k0 + ((sq ^ (row & 7)) << 3);
            gload16(A  + (size_t)(m0 + row) * K + ks, (const char*)As + chunk * 1024);
            gload16(Bt + (size_t)(n0 + row) * K + ks, (const char*)Bs + chunk * 1024);
        }
        __syncthreads();
        #pragma unroll
        for (int kk = 0; kk < 2; ++kk) {
            bf8 af[4], bg[4];
            #pragma unroll
            for (int f = 0; f < 4; ++f) {
                const int ra = wm + f * 16 + lr;
                af[f] = *(const bf8*)((const char*)As + ra * 128 +
                        ((((kk << 2) | lg) ^ (ra & 7)) << 4));
                const int rb = wn + f * 16 + lr;
                bg[f] = *(const bf8*)((const char*)Bs + rb * 128 +
                        ((((kk << 2) | lg) ^ (rb & 7)) << 4));
            }
            #pragma unroll
            for (int fm = 0; fm < 4; ++fm)
                #pragma unroll
                for (int fn = 0; fn < 4; ++fn)
                    acc[fm][fn] = __builtin_amdgcn_mfma_f32_16x16x32_bf16(
                        af[fm], bg[fn], acc[fm][fn], 0, 0, 0);
        }
        __syncthreads();
    }

    float bv[4];
    #pragma unroll
    for (int fn = 0; fn < 4; ++fn) bv[fn] = bias[n0 + wn + fn * 16 + lr];
    #pragma unroll
    for (int fm = 0; fm < 4; ++fm)
        #pragma unroll
        for (int j = 0; j < 4; ++j) {
            const int row = m0 + wm + fm * 16 + lg * 4 + j;
            #pragma unroll
            for (int fn = 0; fn < 4; ++fn) {
                float v = acc[fm][fn][j] + bv[fn];
                if (RELU) v = fmaxf(v, 0.f);
                const size_t off = (size_t)row * N + n0 + wn + fn * 16 + lr;
                if (RESID) Cf[off] += v;
                if (OBF)   Cb[off] = f2b(v);
            }
        }
}

// ---------------- MFMA flash attention ----------------
// qkv bf16 rows [q|k|v] stride 768, head offset h*64. Keys valid iff 1<=t<=count[b].
// Block: (b, h, 64-q tile); 4 waves x 16 q-rows. Swapped QK^T so lane lr owns q-row.

__global__ __launch_bounds__(256) void k_attn_mfma(
    const u16* __restrict__ qkv, const int* __restrict__ counts,
    u16* __restrict__ out)
{
    __shared__ u16 Ks[4096];      // [64 key][64 dh] swizzled
    __shared__ u16 Vt[4096];      // [64 dh][64 key] swizzled
    __shared__ u16 Ps[4][1024];   // per-wave P [16 q][64 key] swizzled
    const int tid = threadIdx.x;
    const int w = tid >> 6, lane = tid & 63;
    const int lr = lane & 15, lg = lane >> 4;
    const int b = blockIdx.z, hh = blockIdx.y;
    const int q0 = blockIdx.x * 64;
    const int kmax = min(counts[b], SEQ - 1);
    const int ntiles = (kmax + 64) >> 6;     // ceil((kmax+1)/64)
    const size_t bb = (size_t)b * SEQ;

    // Q fragments (B operand): q-row = q0 + w*16 + lr, dh = kk*32 + lg*8..+7
    const int qrow = q0 + w * 16 + lr;
    const size_t qoff = (bb + (size_t)min(qrow, SEQ - 1)) * 768 + hh * 64 + (lg << 3);
    const bf8 qf0 = *(const bf8*)(qkv + qoff);
    const bf8 qf1 = *(const bf8*)(qkv + qoff + 32);

    const f4 zf = {0.f, 0.f, 0.f, 0.f};
    f4 o_[4];
    #pragma unroll
    for (int fn = 0; fn < 4; ++fn) o_[fn] = zf;
    float mrow = -INFINITY, ssum = 0.f;

    for (int kt = 0; kt < ntiles; ++kt) {
        const int k0 = kt * 64;
        // stage K tile (global_load_lds, pre-swizzled source)
        #pragma unroll
        for (int c = 0; c < 2; ++c) {
            const int chunk = w * 2 + c;
            const int row = chunk * 8 + (lane >> 3);
            const int q = lane & 7;
            const int krow = min(k0 + row, SEQ - 1);
            gload16(qkv + (bb + krow) * 768 + 256 + hh * 64 + ((q ^ (row & 7)) << 3),
                    (const char*)Ks + chunk * 1024);
        }
        // stage V transposed (reg-staged, conflict-free u32 writes)
        {
            const int kk2 = (tid & 31) * 2;
            const int dh0 = (tid >> 5) * 8;
            const int r0 = min(k0 + kk2, SEQ - 1), r1 = min(k0 + kk2 + 1, SEQ - 1);
            const bf8 v0 = *(const bf8*)(qkv + (bb + r0) * 768 + 512 + hh * 64 + dh0);
            const bf8 v1 = *(const bf8*)(qkv + (bb + r1) * 768 + 512 + hh * 64 + dh0);
            #pragma unroll
            for (int e = 0; e < 8; ++e) {
                const int d = dh0 + e;
                const unsigned pk = (unsigned)(u16)v0[e] | ((unsigned)(u16)v1[e] << 16);
                *(unsigned*)((char*)Vt + d * 128 +
                    ((((kk2 >> 3) ^ (d & 7)) << 4)) + ((kk2 & 7) << 1)) = pk;
            }
        }
        __syncthreads();

        // QK^T swapped: sf = K_frag x Q^T -> lane holds S[q=lr][key = fk*16+lg*4+j]
        f4 sf[4];
        #pragma unroll
        for (int fk = 0; fk < 4; ++fk) sf[fk] = zf;
        #pragma unroll
        for (int kk = 0; kk < 2; ++kk) {
            const bf8 qf = kk ? qf1 : qf0;
            #pragma unroll
            for (int fk = 0; fk < 4; ++fk) {
                const int rk = fk * 16 + lr;
                const bf8 kf = *(const bf8*)((const char*)Ks + rk * 128 +
                        ((((kk << 2) | lg) ^ (rk & 7)) << 4));
                sf[fk] = __builtin_amdgcn_mfma_f32_16x16x32_bf16(kf, qf, sf[fk], 0, 0, 0);
            }
        }

        // online softmax (lane owns q-row lr; stats replicated across the 4 lane-groups)
        float sv[4][4];
        float pmax = -INFINITY;
        #pragma unroll
        for (int fk = 0; fk < 4; ++fk)
            #pragma unroll
            for (int j = 0; j < 4; ++j) {
                const int key = k0 + fk * 16 + lg * 4 + j;
                float x = (key >= 1 && key <= kmax) ? sf[fk][j] * 0.125f : -INFINITY;
                sv[fk][j] = x;
                pmax = fmaxf(pmax, x);
            }
        pmax = fmaxf(pmax, __shfl_xor(pmax, 16));
        pmax = fmaxf(pmax, __shfl_xor(pmax, 32));
        const float mnew = fmaxf(mrow, pmax);
        const float fac = __expf(mrow - mnew);   // 0 on first tile
        mrow = mnew;
        float tsum = 0.f;
        #pragma unroll
        for (int fk = 0; fk < 4; ++fk) {
            const float p0 = __expf(sv[fk][0] - mnew);
            const float p1 = __expf(sv[fk][1] - mnew);
            const float p2 = __expf(sv[fk][2] - mnew);
            const float p3 = __expf(sv[fk][3] - mnew);
            tsum += p0 + p1 + p2 + p3;
            ushort4 pk;
            pk.x = f2b(p0); pk.y = f2b(p1); pk.z = f2b(p2); pk.w = f2b(p3);
            *(ushort4*)((char*)Ps[w] + lr * 128 +
                (((((fk << 1) | (lg >> 1)) ^ (lr & 7)) << 4)) + ((lg & 1) << 3)) = pk;
        }
        tsum += __shfl_xor(tsum, 16);
        tsum += __shfl_xor(tsum, 32);
        ssum = ssum * fac + tsum;

        // rescale O accumulators (O rows live at lg*4+j; stats live at lane q)
        #pragma unroll
        for (int j = 0; j < 4; ++j) {
            const float fj = __shfl(fac, lg * 4 + j);
            #pragma unroll
            for (int fn = 0; fn < 4; ++fn) o_[fn][j] *= fj;
        }
        __syncthreads();   // P visible (barrier also orders LDS w.r.t. reads below)

        // PV: O += P x V
        #pragma unroll
        for (int kk = 0; kk < 2; ++kk) {
            const bf8 pa = *(const bf8*)((const char*)Ps[w] + lr * 128 +
                    ((((kk << 2) | lg) ^ (lr & 7)) << 4));
            #pragma unroll
            for (int fn = 0; fn < 4; ++fn) {
                const int rv = fn * 16 + lr;
                const bf8 vf = *(const bf8*)((const char*)Vt + rv * 128 +
                        ((((kk << 2) | lg) ^ (rv & 7)) << 4));
                o_[fn] = __builtin_amdgcn_mfma_f32_16x16x32_bf16(pa, vf, o_[fn], 0, 0, 0);
            }
        }
        __syncthreads();   // everyone done with Ks/Vt/Ps before next stage
    }

    const float inv = 1.f / ssum;
    #pragma unroll
    for (int j = 0; j < 4; ++j) {
        const float ij = __shfl(inv, lg * 4 + j);
        const int qr = q0 + w * 16 + lg * 4 + j;
        if (qr < SEQ) {
            #pragma unroll
            for (int fn = 0; fn < 4; ++fn)
                out[(bb + qr) * DMODEL + hh * 64 + fn * 16 + lr] = f2b(o_[fn][j] * ij);
        }
    }
}

// ---------------- head (fp32, reads h) ----------------

__global__ __launch_bounds__(256) void k_head(
    const float* __restrict__ h, const float* __restrict__ w1,
    const float* __restrict__ b1, const float* __restrict__ w2,
    const float* __restrict__ b2, float* __restrict__ out)
{
    __shared__ float cbuf[DMODEL];
    __shared__ float p1[DMODEL];
    __shared__ float p2[3];
    const int b = blockIdx.x, tid = threadIdx.x;
    cbuf[tid] = h[(size_t)b * SEQ * DMODEL + tid];
    __syncthreads();
    float acc = b1[tid];
    #pragma unroll 8
    for (int k = 0; k < DMODEL; ++k) acc = fmaf(cbuf[k], w1[k * DMODEL + tid], acc);
    p1[tid] = fmaxf(acc, 0.f);
    __syncthreads();
    if (tid < 3) {
        float a = b2[tid];
        for (int k = 0; k < DMODEL; ++k) a = fmaf(p1[k], w2[k * 3 + tid], a);
        p2[tid] = a;
    }
    __syncthreads();
    if (tid < 3) {
        float n2 = p2[0]*p2[0] + p2[1]*p2[1] + p2[2]*p2[2];
        out[b * 3 + tid] = p2[tid] * rsqrtf(n2);
    }
}

// ---------------- launch ----------------

extern "C" void kernel_launch(void* const* d_in, const int* in_sizes, int n_in,
                              void* d_out, int out_size, void* d_ws, size_t ws_size,
                              hipStream_t stream) {
    const float* emb   = (const float*)d_in[0];
    const int*   idx   = (const int*)d_in[1];
    const float* projw = (const float*)d_in[4];
    const float* projb = (const float*)d_in[5];
    const float* cls   = (const float*)d_in[6];
    const float* ln1g  = (const float*)d_in[7];
    const float* ln1b  = (const float*)d_in[8];
    const float* qkvw  = (const float*)d_in[9];
    const float* qkvb  = (const float*)d_in[10];
    const float* outw  = (const float*)d_in[11];
    const float* outb  = (const float*)d_in[12];
    const float* ln2g  = (const float*)d_in[13];
    const float* ln2b  = (const float*)d_in[14];
    const float* ff1w  = (const float*)d_in[15];
    const float* ff1b  = (const float*)d_in[16];
    const float* ff2w  = (const float*)d_in[17];
    const float* ff2b  = (const float*)d_in[18];
    const float* h1w   = (const float*)d_in[19];
    const float* h1b   = (const float*)d_in[20];
    const float* h2w   = (const float*)d_in[21];
    const float* h2b   = (const float*)d_in[22];
    float* out = (float*)d_out;

    char* ws = (char*)d_ws;
    int*   counts = (int*)ws;                               // @0
    int*   pos    = (int*)(ws + 4096);
    float* h      = (float*)(ws + 135168);                  // [M][256] f32, 44.0MB
    u16*   ybf    = (u16*)(ws + 44175360);                  // [M][256] bf16 (ln out / attn out)
    u16*   qkvb16 = (u16*)(ws + 66195456);                  // [M+64][768] bf16
    u16*   ffb    = (u16*)(ws + 132354048);                 // [M][1024] bf16
    u16*   wq     = (u16*)(ws + 220434432);                 // 4 x [768][256]
    u16*   wo     = (u16*)(ws + 222007296);                 // 4 x [256][256]
    u16*   w1     = (u16*)(ws + 222531584);                 // 4 x [1024][256]
    u16*   w2     = (u16*)(ws + 224628736);                 // 4 x [256][1024]

    k_zero_counts<<<1, 64, 0, stream>>>(counts);
    k_pos<<<NDOM / 256, 256, 0, stream>>>(idx, counts, pos);
    k_init_h<<<2688, 256, 0, stream>>>(h, cls);
    k_proj_scatter<<<NDOM, 256, 0, stream>>>(emb, idx, pos, projw, projb, h);

    for (int l = 0; l < NLAYER; ++l) {
        k_wt<<<768,  256, 0, stream>>>(qkvw + (size_t)l * 196608, wq + (size_t)l * 196608, 256, 768);
        k_wt<<<256,  256, 0, stream>>>(outw + (size_t)l * 65536,  wo + (size_t)l * 65536,  256, 256);
        k_wt<<<1024, 256, 0, stream>>>(ff1w + (size_t)l * 262144, w1 + (size_t)l * 262144, 256, 1024);
        k_wt<<<1024, 256, 0, stream>>>(ff2w + (size_t)l * 262144, w2 + (size_t)l * 262144, 1024, 256);
    }

    for (int l = 0; l < NLAYER; ++l) {
        k_ln_bf<<<MROWS / 4, 256, 0, stream>>>(h, ln1g + l * DMODEL, ln1b + l * DMODEL, ybf);
        k_gemm_bf<0,0,1><<<dim3(6, 336), 256, 0, stream>>>(
            ybf, wq + (size_t)l * 196608, qkvb + l * 768, nullptr, qkvb16, 256, 768);
        k_attn_mfma<<<dim3(11, NHEAD, BATCH), 256, 0, stream>>>(qkvb16, counts, ybf);
        k_gemm_bf<0,1,0><<<dim3(2, 336), 256, 0, stream>>>(
            ybf, wo + (size_t)l * 65536, outb + l * DMODEL, h, nullptr, 256, 256);
        k_ln_bf<<<MROWS / 4, 256, 0, stream>>>(h, ln2g + l * DMODEL, ln2b + l * DMODEL, ybf);
        k_gemm_bf<1,0,1><<<dim3(8, 336), 256, 0, stream>>>(
            ybf, w1 + (size_t)l * 262144, ff1b + l * DFFN, nullptr, ffb, 256, 1024);
        k_gemm_bf<0,1,0><<<dim3(2, 336), 256, 0, stream>>>(
            ffb, w2 + (size_t)l * 262144, ff2b + l * DMODEL, h, nullptr, 1024, 256);
    }

    k_head<<<BATCH, 256, 0, stream>>>(h, h1w, h1b, h2w, h2b, out);
}

// Round 5
// 1165.557 us; speedup vs baseline: 13.7238x; 1.1891x over previous
//
#include <hip/hip_runtime.h>
#include <cstdint>
#include <cstddef>

#define NDOM   32768
#define DIN    128
#define DMODEL 256
#define NHEAD  4
#define NLAYER 4
#define DFFN   1024
#define BATCH  64
#define SEQ    672
#define DHEAD  64
#define MROWS  (BATCH*SEQ)   // 43008

typedef unsigned short u16;
typedef __attribute__((ext_vector_type(8))) short bf8;   // 8 bf16 (4 VGPRs)
typedef __attribute__((ext_vector_type(4))) float f4;    // MFMA accumulator

__device__ inline u16 f2b(float x) {            // f32 -> bf16 RNE
    union { float f; unsigned u; } c; c.f = x;
    unsigned r = c.u + 0x7fffu + ((c.u >> 16) & 1u);
    return (u16)(r >> 16);
}

__device__ inline void gload16(const void* g, const void* l) {
    __builtin_amdgcn_global_load_lds(
        (const __attribute__((address_space(1))) void*)g,
        (__attribute__((address_space(3))) void*)l, 16, 0, 0);
}

// ---------------- setup ----------------

__global__ void k_zero_counts(int* __restrict__ counts) {
    if (threadIdx.x < BATCH) counts[threadIdx.x] = 0;
}

__global__ void k_pos(const int* __restrict__ idx, int* __restrict__ counts,
                      int* __restrict__ pos) {
    int i = blockIdx.x * blockDim.x + threadIdx.x;
    if (i < NDOM) pos[i] = atomicAdd(&counts[idx[i]], 1);
}

__global__ void k_init_h(float* __restrict__ h, const float* __restrict__ cls) {
    const float4* cls4 = (const float4*)cls;
    float4* h4 = (float4*)h;
    const int total4 = MROWS * DMODEL / 4;
    for (int f = blockIdx.x * blockDim.x + threadIdx.x; f < total4;
         f += gridDim.x * blockDim.x) {
        int d4 = f & 63;
        int t  = (f >> 6) % SEQ;
        h4[f] = (t == 0) ? cls4[d4] : make_float4(0.f, 0.f, 0.f, 0.f);
    }
}

// f32 -> bf16 bulk convert (vectorized)
__global__ void k_b16(const float* __restrict__ x, u16* __restrict__ y, int n4) {
    int i = blockIdx.x * 256 + threadIdx.x;
    if (i < n4) {
        float4 v = ((const float4*)x)[i];
        ushort4 o;
        o.x = f2b(v.x); o.y = f2b(v.y); o.z = f2b(v.z); o.w = f2b(v.w);
        ((ushort4*)y)[i] = o;
    }
}

// merged weight convert+transpose, one 64x64 tile per block, LDS-coalesced.
// Wt[n][k] = bf16(W[k][n]) for proj/qkv/out/ff1/ff2 (all layers).
__global__ __launch_bounds__(256) void k_wt_all(
    const float* __restrict__ projw, const float* __restrict__ qkvw,
    const float* __restrict__ outw,  const float* __restrict__ ff1w,
    const float* __restrict__ ff2w,
    u16* __restrict__ wpj, u16* __restrict__ wq, u16* __restrict__ wo,
    u16* __restrict__ w1,  u16* __restrict__ w2)
{
    __shared__ float t[64][65];
    const int tile = blockIdx.x;
    const float* W; u16* D; int K, N, local;
    if (tile < 8)        { W = projw; D = wpj; K = 128;  N = 256;  local = tile; }
    else if (tile < 200) { int l = (tile-8)/48;   local = (tile-8)%48;
                           W = qkvw + (size_t)l*196608; D = wq + (size_t)l*196608; K = 256;  N = 768; }
    else if (tile < 264) { int l = (tile-200)/16; local = (tile-200)%16;
                           W = outw + (size_t)l*65536;  D = wo + (size_t)l*65536;  K = 256;  N = 256; }
    else if (tile < 520) { int l = (tile-264)/64; local = (tile-264)%64;
                           W = ff1w + (size_t)l*262144; D = w1 + (size_t)l*262144; K = 256;  N = 1024; }
    else                 { int l = (tile-520)/64; local = (tile-520)%64;
                           W = ff2w + (size_t)l*262144; D = w2 + (size_t)l*262144; K = 1024; N = 256; }
    const int ntn = N >> 6;
    const int tk = local / ntn, tn = local % ntn;
    const int r = threadIdx.x >> 6, c = threadIdx.x & 63;
    #pragma unroll 4
    for (int rr = r; rr < 64; rr += 4)
        t[rr][c] = W[(size_t)(tk*64 + rr) * N + tn*64 + c];
    __syncthreads();
    #pragma unroll 4
    for (int rr = r; rr < 64; rr += 4)
        D[(size_t)(tn*64 + rr) * K + tk*64 + c] = f2b(t[c][rr]);
}

// scatter projected rows into padded layout: h[idx[i], pos[i]+1, :] = xp[i, :]
__global__ __launch_bounds__(256) void k_scatter(
    const float* __restrict__ xp, const int* __restrict__ idx,
    const int* __restrict__ pos, float* __restrict__ h)
{
    const int i = blockIdx.x * 4 + (threadIdx.x >> 6);
    const int lane = threadIdx.x & 63;
    const int p = pos[i] + 1;
    if (p >= SEQ) return;   // reference drops OOB scatter writes
    const size_t row = (size_t)idx[i] * SEQ + p;
    ((float4*)(h + row * DMODEL))[lane] = ((const float4*)(xp + (size_t)i * DMODEL))[lane];
}

// ---------------- layernorm -> bf16 ----------------

__global__ __launch_bounds__(256) void k_ln_bf(
    const float* __restrict__ x, const float* __restrict__ g,
    const float* __restrict__ bt, u16* __restrict__ y)
{
    const int row  = blockIdx.x * 4 + (threadIdx.x >> 6);
    const int lane = threadIdx.x & 63;
    float4 v = ((const float4*)(x + (size_t)row * DMODEL))[lane];
    float s = v.x + v.y + v.z + v.w;
    #pragma unroll
    for (int off = 32; off >= 1; off >>= 1) s += __shfl_xor(s, off);
    const float m = s * (1.f / DMODEL);
    const float d0 = v.x - m, d1 = v.y - m, d2 = v.z - m, d3 = v.w - m;
    float q = d0*d0 + d1*d1 + d2*d2 + d3*d3;
    #pragma unroll
    for (int off = 32; off >= 1; off >>= 1) q += __shfl_xor(q, off);
    const float rstd = rsqrtf(q * (1.f / DMODEL) + 1e-5f);
    const float4 gv = ((const float4*)g)[lane];
    const float4 bv = ((const float4*)bt)[lane];
    ushort4 o;
    o.x = f2b(d0 * rstd * gv.x + bv.x);
    o.y = f2b(d1 * rstd * gv.y + bv.y);
    o.z = f2b(d2 * rstd * gv.z + bv.z);
    o.w = f2b(d3 * rstd * gv.w + bv.w);
    ((ushort4*)(y + (size_t)row * DMODEL))[lane] = o;
}

// ---------------- bf16 MFMA GEMM: C[M,N] = A[M,K] @ Bt[N,K]^T + bias ----------------
// 128x128 tile, BK=64, 4 waves (2x2), 4x4 16x16x32 fragments per wave.
// LDS rows 128B, XOR-swizzled: slot ^= (row&7).

template<int RELU, int RESID, int OBF, int OF32>
__global__ __launch_bounds__(256) void k_gemm_bf(
    const u16* __restrict__ A, const u16* __restrict__ Bt,
    const float* __restrict__ bias, float* __restrict__ Cf,
    u16* __restrict__ Cb, int K, int N)
{
    __shared__ u16 As[8192];   // [128][64] bf16, swizzled
    __shared__ u16 Bs[8192];
    const int tid = threadIdx.x;
    const int w = tid >> 6, lane = tid & 63;
    const int lr = lane & 15, lg = lane >> 4;
    const int m0 = blockIdx.y * 128, n0 = blockIdx.x * 128;
    const int wm = (w >> 1) * 64, wn = (w & 1) * 64;

    const f4 zf = {0.f, 0.f, 0.f, 0.f};
    f4 acc[4][4];
    #pragma unroll
    for (int i = 0; i < 4; ++i)
        #pragma unroll
        for (int j = 0; j < 4; ++j) acc[i][j] = zf;

    const int srow8 = lane >> 3;   // 0..7 within chunk
    const int sq = lane & 7;       // 16B slot within row

    for (int k0 = 0; k0 < K; k0 += 64) {
        #pragma unroll
        for (int c = 0; c < 4; ++c) {
            const int chunk = w * 4 + c;               // 0..15 (1KB each)
            const int row = chunk * 8 + srow8;         // 0..127
            const int ks = k0 + ((sq ^ (row & 7)) << 3);
            gload16(A  + (size_t)(m0 + row) * K + ks, (const char*)As + chunk * 1024);
            gload16(Bt + (size_t)(n0 + row) * K + ks, (const char*)Bs + chunk * 1024);
        }
        __syncthreads();
        #pragma unroll
        for (int kk = 0; kk < 2; ++kk) {
            bf8 af[4], bg[4];
            #pragma unroll
            for (int f = 0; f < 4; ++f) {
                const int ra = wm + f * 16 + lr;
                af[f] = *(const bf8*)((const char*)As + ra * 128 +
                        ((((kk << 2) | lg) ^ (ra & 7)) << 4));
                const int rb = wn + f * 16 + lr;
                bg[f] = *(const bf8*)((const char*)Bs + rb * 128 +
                        ((((kk << 2) | lg) ^ (rb & 7)) << 4));
            }
            #pragma unroll
            for (int fm = 0; fm < 4; ++fm)
                #pragma unroll
                for (int fn = 0; fn < 4; ++fn)
                    acc[fm][fn] = __builtin_amdgcn_mfma_f32_16x16x32_bf16(
                        af[fm], bg[fn], acc[fm][fn], 0, 0, 0);
        }
        __syncthreads();
    }

    float bv[4];
    #pragma unroll
    for (int fn = 0; fn < 4; ++fn) bv[fn] = bias[n0 + wn + fn * 16 + lr];
    #pragma unroll
    for (int fm = 0; fm < 4; ++fm)
        #pragma unroll
        for (int j = 0; j < 4; ++j) {
            const int row = m0 + wm + fm * 16 + lg * 4 + j;
            #pragma unroll
            for (int fn = 0; fn < 4; ++fn) {
                float v = acc[fm][fn][j] + bv[fn];
                if (RELU) v = fmaxf(v, 0.f);
                const size_t off = (size_t)row * N + n0 + wn + fn * 16 + lr;
                if (RESID) Cf[off] += v;
                if (OF32)  Cf[off] = v;
                if (OBF)   Cb[off] = f2b(v);
            }
        }
}

// ---------------- MFMA flash attention ----------------
// qkv bf16 rows [q|k|v] stride 768, head offset h*64. Keys valid iff 1<=t<=count[b].
// Block: (b, h, 64-q tile); 4 waves x 16 q-rows. Swapped QK^T so lane lr owns q-row.
// Dead query tiles (q0 > kmax) exit early: their rows never feed live rows.

__global__ __launch_bounds__(256) void k_attn_mfma(
    const u16* __restrict__ qkv, const int* __restrict__ counts,
    u16* __restrict__ out)
{
    __shared__ u16 Ks[4096];      // [64 key][64 dh] swizzled
    __shared__ u16 Vt[4096];      // [64 dh][64 key] swizzled
    __shared__ u16 Ps[4][1024];   // per-wave P [16 q][64 key] swizzled
    const int tid = threadIdx.x;
    const int w = tid >> 6, lane = tid & 63;
    const int lr = lane & 15, lg = lane >> 4;
    const int b = blockIdx.z, hh = blockIdx.y;
    const int q0 = blockIdx.x * 64;
    const int kmax = min(counts[b], SEQ - 1);
    if (q0 > kmax) return;                   // dead query tile
    const int ntiles = (kmax + 64) >> 6;     // ceil((kmax+1)/64)
    const size_t bb = (size_t)b * SEQ;

    // Q fragments (B operand): q-row = q0 + w*16 + lr, dh = kk*32 + lg*8..+7
    const int qrow = q0 + w * 16 + lr;
    const size_t qoff = (bb + (size_t)min(qrow, SEQ - 1)) * 768 + hh * 64 + (lg << 3);
    const bf8 qf0 = *(const bf8*)(qkv + qoff);
    const bf8 qf1 = *(const bf8*)(qkv + qoff + 32);

    const f4 zf = {0.f, 0.f, 0.f, 0.f};
    f4 o_[4];
    #pragma unroll
    for (int fn = 0; fn < 4; ++fn) o_[fn] = zf;
    float mrow = -INFINITY, ssum = 0.f;

    for (int kt = 0; kt < ntiles; ++kt) {
        const int k0 = kt * 64;
        // stage K tile (global_load_lds, pre-swizzled source)
        #pragma unroll
        for (int c = 0; c < 2; ++c) {
            const int chunk = w * 2 + c;
            const int row = chunk * 8 + (lane >> 3);
            const int q = lane & 7;
            const int krow = min(k0 + row, SEQ - 1);
            gload16(qkv + (bb + krow) * 768 + 256 + hh * 64 + ((q ^ (row & 7)) << 3),
                    (const char*)Ks + chunk * 1024);
        }
        // stage V transposed (reg-staged, conflict-free u32 writes)
        {
            const int kk2 = (tid & 31) * 2;
            const int dh0 = (tid >> 5) * 8;
            const int r0 = min(k0 + kk2, SEQ - 1), r1 = min(k0 + kk2 + 1, SEQ - 1);
            const bf8 v0 = *(const bf8*)(qkv + (bb + r0) * 768 + 512 + hh * 64 + dh0);
            const bf8 v1 = *(const bf8*)(qkv + (bb + r1) * 768 + 512 + hh * 64 + dh0);
            #pragma unroll
            for (int e = 0; e < 8; ++e) {
                const int d = dh0 + e;
                const unsigned pk = (unsigned)(u16)v0[e] | ((unsigned)(u16)v1[e] << 16);
                *(unsigned*)((char*)Vt + d * 128 +
                    ((((kk2 >> 3) ^ (d & 7)) << 4)) + ((kk2 & 7) << 1)) = pk;
            }
        }
        __syncthreads();

        // QK^T swapped: sf = K_frag x Q^T -> lane holds S[q=lr][key = fk*16+lg*4+j]
        f4 sf[4];
        #pragma unroll
        for (int fk = 0; fk < 4; ++fk) sf[fk] = zf;
        #pragma unroll
        for (int kk = 0; kk < 2; ++kk) {
            const bf8 qf = kk ? qf1 : qf0;
            #pragma unroll
            for (int fk = 0; fk < 4; ++fk) {
                const int rk = fk * 16 + lr;
                const bf8 kf = *(const bf8*)((const char*)Ks + rk * 128 +
                        ((((kk << 2) | lg) ^ (rk & 7)) << 4));
                sf[fk] = __builtin_amdgcn_mfma_f32_16x16x32_bf16(kf, qf, sf[fk], 0, 0, 0);
            }
        }

        // online softmax (lane owns q-row lr; stats replicated across the 4 lane-groups)
        float sv[4][4];
        float pmax = -INFINITY;
        #pragma unroll
        for (int fk = 0; fk < 4; ++fk)
            #pragma unroll
            for (int j = 0; j < 4; ++j) {
                const int key = k0 + fk * 16 + lg * 4 + j;
                float x = (key >= 1 && key <= kmax) ? sf[fk][j] * 0.125f : -INFINITY;
                sv[fk][j] = x;
                pmax = fmaxf(pmax, x);
            }
        pmax = fmaxf(pmax, __shfl_xor(pmax, 16));
        pmax = fmaxf(pmax, __shfl_xor(pmax, 32));
        const float mnew = fmaxf(mrow, pmax);
        const float fac = __expf(mrow - mnew);   // 0 on first tile
        mrow = mnew;
        float tsum = 0.f;
        #pragma unroll
        for (int fk = 0; fk < 4; ++fk) {
            const float p0 = __expf(sv[fk][0] - mnew);
            const float p1 = __expf(sv[fk][1] - mnew);
            const float p2 = __expf(sv[fk][2] - mnew);
            const float p3 = __expf(sv[fk][3] - mnew);
            tsum += p0 + p1 + p2 + p3;
            ushort4 pk;
            pk.x = f2b(p0); pk.y = f2b(p1); pk.z = f2b(p2); pk.w = f2b(p3);
            *(ushort4*)((char*)Ps[w] + lr * 128 +
                (((((fk << 1) | (lg >> 1)) ^ (lr & 7)) << 4)) + ((lg & 1) << 3)) = pk;
        }
        tsum += __shfl_xor(tsum, 16);
        tsum += __shfl_xor(tsum, 32);
        ssum = ssum * fac + tsum;

        // rescale O accumulators (O rows live at lg*4+j; stats live at lane q)
        #pragma unroll
        for (int j = 0; j < 4; ++j) {
            const float fj = __shfl(fac, lg * 4 + j);
            #pragma unroll
            for (int fn = 0; fn < 4; ++fn) o_[fn][j] *= fj;
        }
        __syncthreads();   // P visible (barrier also orders LDS w.r.t. reads below)

        // PV: O += P x V
        #pragma unroll
        for (int kk = 0; kk < 2; ++kk) {
            const bf8 pa = *(const bf8*)((const char*)Ps[w] + lr * 128 +
                    ((((kk << 2) | lg) ^ (lr & 7)) << 4));
            #pragma unroll
            for (int fn = 0; fn < 4; ++fn) {
                const int rv = fn * 16 + lr;
                const bf8 vf = *(const bf8*)((const char*)Vt + rv * 128 +
                        ((((kk << 2) | lg) ^ (rv & 7)) << 4));
                o_[fn] = __builtin_amdgcn_mfma_f32_16x16x32_bf16(pa, vf, o_[fn], 0, 0, 0);
            }
        }
        __syncthreads();   // everyone done with Ks/Vt/Ps before next stage
    }

    const float inv = 1.f / ssum;
    #pragma unroll
    for (int j = 0; j < 4; ++j) {
        const float ij = __shfl(inv, lg * 4 + j);
        const int qr = q0 + w * 16 + lg * 4 + j;
        if (qr < SEQ) {
            #pragma unroll
            for (int fn = 0; fn < 4; ++fn)
                out[(bb + qr) * DMODEL + hh * 64 + fn * 16 + lr] = f2b(o_[fn][j] * ij);
        }
    }
}

// ---------------- head (fp32, reads h) ----------------

__global__ __launch_bounds__(256) void k_head(
    const float* __restrict__ h, const float* __restrict__ w1,
    const float* __restrict__ b1, const float* __restrict__ w2,
    const float* __restrict__ b2, float* __restrict__ out)
{
    __shared__ float cbuf[DMODEL];
    __shared__ float p1[DMODEL];
    __shared__ float p2[3];
    const int b = blockIdx.x, tid = threadIdx.x;
    cbuf[tid] = h[(size_t)b * SEQ * DMODEL + tid];
    __syncthreads();
    float acc = b1[tid];
    #pragma unroll 8
    for (int k = 0; k < DMODEL; ++k) acc = fmaf(cbuf[k], w1[k * DMODEL + tid], acc);
    p1[tid] = fmaxf(acc, 0.f);
    __syncthreads();
    if (tid < 3) {
        float a = b2[tid];
        for (int k = 0; k < DMODEL; ++k) a = fmaf(p1[k], w2[k * 3 + tid], a);
        p2[tid] = a;
    }
    __syncthreads();
    if (tid < 3) {
        float n2 = p2[0]*p2[0] + p2[1]*p2[1] + p2[2]*p2[2];
        out[b * 3 + tid] = p2[tid] * rsqrtf(n2);
    }
}

// ---------------- launch ----------------

extern "C" void kernel_launch(void* const* d_in, const int* in_sizes, int n_in,
                              void* d_out, int out_size, void* d_ws, size_t ws_size,
                              hipStream_t stream) {
    const float* emb   = (const float*)d_in[0];
    const int*   idx   = (const int*)d_in[1];
    const float* projw = (const float*)d_in[4];
    const float* projb = (const float*)d_in[5];
    const float* cls   = (const float*)d_in[6];
    const float* ln1g  = (const float*)d_in[7];
    const float* ln1b  = (const float*)d_in[8];
    const float* qkvw  = (const float*)d_in[9];
    const float* qkvb  = (const float*)d_in[10];
    const float* outw  = (const float*)d_in[11];
    const float* outb  = (const float*)d_in[12];
    const float* ln2g  = (const float*)d_in[13];
    const float* ln2b  = (const float*)d_in[14];
    const float* ff1w  = (const float*)d_in[15];
    const float* ff1b  = (const float*)d_in[16];
    const float* ff2w  = (const float*)d_in[17];
    const float* ff2b  = (const float*)d_in[18];
    const float* h1w   = (const float*)d_in[19];
    const float* h1b   = (const float*)d_in[20];
    const float* h2w   = (const float*)d_in[21];
    const float* h2b   = (const float*)d_in[22];
    float* out = (float*)d_out;

    char* ws = (char*)d_ws;
    int*   counts = (int*)ws;                               // @0
    int*   pos    = (int*)(ws + 4096);
    float* h      = (float*)(ws + 135168);                  // [M][256] f32
    u16*   ybf    = (u16*)(ws + 44175360);                  // [M][256] bf16
    u16*   qkvb16 = (u16*)(ws + 66195456);                  // [M+64][768] bf16
    u16*   ffb    = (u16*)(ws + 132354048);                 // [M][1024] bf16
    u16*   wq     = (u16*)(ws + 220434432);                 // 4 x [768][256]
    u16*   wo     = (u16*)(ws + 222007296);                 // 4 x [256][256]
    u16*   w1     = (u16*)(ws + 222531584);                 // 4 x [1024][256]
    u16*   w2     = (u16*)(ws + 224628736);                 // 4 x [256][1024]
    u16*   wpj    = (u16*)(ws + 226725888);                 // [256][128]
    // aliases (pre-layer-loop only): embbf over qkvb16, xp over ffb
    u16*   embbf  = qkvb16;                                 // [NDOM][128] bf16
    float* xp     = (float*)ffb;                            // [NDOM][256] f32

    k_zero_counts<<<1, 64, 0, stream>>>(counts);
    k_pos<<<NDOM / 256, 256, 0, stream>>>(idx, counts, pos);
    k_b16<<<(NDOM * DIN / 4) / 256, 256, 0, stream>>>(emb, embbf, NDOM * DIN / 4);
    k_wt_all<<<776, 256, 0, stream>>>(projw, qkvw, outw, ff1w, ff2w,
                                      wpj, wq, wo, w1, w2);
    k_init_h<<<2688, 256, 0, stream>>>(h, cls);
    k_gemm_bf<0,0,0,1><<<dim3(2, 256), 256, 0, stream>>>(
        embbf, wpj, projb, xp, nullptr, DIN, DMODEL);
    k_scatter<<<NDOM / 4, 256, 0, stream>>>(xp, idx, pos, h);

    for (int l = 0; l < NLAYER; ++l) {
        k_ln_bf<<<MROWS / 4, 256, 0, stream>>>(h, ln1g + l * DMODEL, ln1b + l * DMODEL, ybf);
        k_gemm_bf<0,0,1,0><<<dim3(6, 336), 256, 0, stream>>>(
            ybf, wq + (size_t)l * 196608, qkvb + l * 768, nullptr, qkvb16, 256, 768);
        k_attn_mfma<<<dim3(11, NHEAD, BATCH), 256, 0, stream>>>(qkvb16, counts, ybf);
        k_gemm_bf<0,1,0,0><<<dim3(2, 336), 256, 0, stream>>>(
            ybf, wo + (size_t)l * 65536, outb + l * DMODEL, h, nullptr, 256, 256);
        k_ln_bf<<<MROWS / 4, 256, 0, stream>>>(h, ln2g + l * DMODEL, ln2b + l * DMODEL, ybf);
        k_gemm_bf<1,0,1,0><<<dim3(8, 336), 256, 0, stream>>>(
            ybf, w1 + (size_t)l * 262144, ff1b + l * DFFN, nullptr, ffb, 256, 1024);
        k_gemm_bf<0,1,0,0><<<dim3(2, 336), 256, 0, stream>>>(
            ffb, w2 + (size_t)l * 262144, ff2b + l * DMODEL, h, nullptr, 1024, 256);
    }

    k_head<<<BATCH, 256, 0, stream>>>(h, h1w, h1b, h2w, h2b, out);
}